// Round 1
// baseline (1575.809 us; speedup 1.0000x reference)
//
#include <hip/hip_runtime.h>
#include <math.h>

#define NN 20000
#define EE 200000
// MUL=128, D=512, EDGE_ATTR=32, HID=32

__device__ __forceinline__ float sspf(float x){
    float sp = (x > 20.f) ? x : log1pf(expf(x));
    return sp - 0.69314718056f;
}

__device__ __forceinline__ void fma8(float* acc, const float* base, float w){
    const float4 a = ((const float4*)base)[0];
    const float4 b = ((const float4*)base)[1];
    acc[0]+=a.x*w; acc[1]+=a.y*w; acc[2]+=a.z*w; acc[3]+=a.w*w;
    acc[4]+=b.x*w; acc[5]+=b.y*w; acc[6]+=b.z*w; acc[7]+=b.w*w;
}

// ---------------- K1: pre irrep_linear -> p1, sdst (p0 consumed in-LDS) ----
__global__ __launch_bounds__(256) void k_pre(
    const float* __restrict__ x, const float* __restrict__ Wp0,
    const float* __restrict__ bp0, const float* __restrict__ Wp1,
    const float* __restrict__ Ws1,
    float* __restrict__ p1, float* __restrict__ sdst)
{
    __shared__ float xl[512][8];    // transposed [feature][node]
    __shared__ float p0l[8][128];
    const int tid = threadIdx.x;
    const int n0 = blockIdx.x * 8;

    for (int it = 0; it < 4; ++it){
        int idx = tid + 256*it;           // 0..1023 float4 slots
        int node = idx >> 7, o4 = idx & 127;
        float4 v = ((const float4*)(x + (size_t)(n0+node)*512))[o4];
        xl[o4*4+0][node]=v.x; xl[o4*4+1][node]=v.y;
        xl[o4*4+2][node]=v.z; xl[o4*4+3][node]=v.w;
    }
    __syncthreads();

    const int j = tid;
    float acc1[8] = {0,0,0,0,0,0,0,0};
    float acc2[8] = {0,0,0,0,0,0,0,0};
    const int o2 = j + 128;               // p1-index in [128,384)
    const int v2 = o2/3, m2 = o2%3;

    if (j < 128){
        for (int u = 0; u < 128; ++u){
            float w1 = Wp0[u*128 + j];
            float w2 = Wp1[u*128 + v2];
            fma8(acc1, &xl[u][0], w1);
            fma8(acc2, &xl[128 + u*3 + m2][0], w2);
        }
        float b = bp0[j];
        #pragma unroll
        for (int n = 0; n < 8; ++n) p0l[n][j] = acc1[n] + b;
    } else {
        const int o1 = j - 128, v1 = o1/3, m1 = o1%3;
        for (int u = 0; u < 128; ++u){
            float w1 = Wp1[u*128 + v1];
            float w2 = Wp1[u*128 + v2];
            fma8(acc1, &xl[128 + u*3 + m1][0], w1);
            fma8(acc2, &xl[128 + u*3 + m2][0], w2);
        }
        #pragma unroll
        for (int n = 0; n < 8; ++n) p1[(size_t)(n0+n)*384 + (j-128)] = acc1[n];
    }
    #pragma unroll
    for (int n = 0; n < 8; ++n) p1[(size_t)(n0+n)*384 + o2] = acc2[n];
    __syncthreads();

    // sdst = p0 @ (Ws1[0:128] + Ws1[128:256])  (the dst-only part of s0@W_s1)
    {
        int n = tid >> 5, h = tid & 31;
        float s = 0.f;
        for (int u = 0; u < 128; ++u){
            float wc = Ws1[u*32 + h] + Ws1[(128+u)*32 + h];
            s += p0l[n][u] * wc;
        }
        sdst[(size_t)(n0+n)*32 + h] = s;
    }
}

// ---------------- K2: gate + node irrep_linear -> self_x -------------------
__global__ __launch_bounds__(256) void k_gate_nd(
    const float* __restrict__ x,
    const float* __restrict__ Wg1, const float* __restrict__ bg1,
    const float* __restrict__ Wg2, const float* __restrict__ bg2,
    const float* __restrict__ Wnd0, const float* __restrict__ bnd0,
    const float* __restrict__ Wnd1,
    float* __restrict__ self_x)
{
    __shared__ float xl[512][8];
    __shared__ float tl[256][8];   // t, then reused for g
    __shared__ float hl[256][8];
    const int tid = threadIdx.x;
    const int n0 = blockIdx.x * 8;

    for (int it = 0; it < 4; ++it){
        int idx = tid + 256*it;
        int node = idx >> 7, o4 = idx & 127;
        float4 v = ((const float4*)(x + (size_t)(n0+node)*512))[o4];
        xl[o4*4+0][node]=v.x; xl[o4*4+1][node]=v.y;
        xl[o4*4+2][node]=v.z; xl[o4*4+3][node]=v.w;
    }
    __syncthreads();

    { // t = [x0, n1]
        int jj = tid;
        if (jj < 128){
            #pragma unroll
            for (int n = 0; n < 8; ++n) tl[jj][n] = xl[jj][n];
        } else {
            int u = jj - 128;
            #pragma unroll
            for (int n = 0; n < 8; ++n){
                float a = xl[128+u*3][n], b = xl[128+u*3+1][n], c = xl[128+u*3+2][n];
                tl[jj][n] = sqrtf((a*a + b*b + c*c) * (1.f/3.f));
            }
        }
    }
    __syncthreads();

    { // h = silu(t @ Wg1 + bg1)
        float acc[8] = {0,0,0,0,0,0,0,0};
        for (int k = 0; k < 256; ++k){
            float w = Wg1[k*256 + tid];
            fma8(acc, &tl[k][0], w);
        }
        float b = bg1[tid];
        #pragma unroll
        for (int n = 0; n < 8; ++n){
            float v = acc[n] + b;
            hl[tid][n] = v / (1.f + expf(-v));
        }
    }
    __syncthreads();

    { // g = h @ Wg2 + bg2  (stored into tl; tl is dead after the barrier)
        float acc[8] = {0,0,0,0,0,0,0,0};
        for (int k = 0; k < 256; ++k){
            float w = Wg2[k*256 + tid];
            fma8(acc, &hl[k][0], w);
        }
        float b = bg2[tid];
        #pragma unroll
        for (int n = 0; n < 8; ++n) tl[tid][n] = acc[n] + b;
    }
    __syncthreads();

    { // xg in-place into xl
        int jj = tid;
        if (jj < 128){
            #pragma unroll
            for (int n = 0; n < 8; ++n) xl[jj][n] = tl[jj][n];
        } else {
            int u = jj - 128;
            #pragma unroll
            for (int n = 0; n < 8; ++n){
                float g1 = tl[128+u][n];
                xl[128+u*3  ][n] *= g1;
                xl[128+u*3+1][n] *= g1;
                xl[128+u*3+2][n] *= g1;
            }
        }
    }
    __syncthreads();

    // nd irrep_linear
    const int j = tid;
    float acc1[8] = {0,0,0,0,0,0,0,0};
    float acc2[8] = {0,0,0,0,0,0,0,0};
    const int o2 = j + 128;
    const int v2 = o2/3, m2 = o2%3;
    if (j < 128){
        for (int u = 0; u < 128; ++u){
            float w1 = Wnd0[u*128 + j];
            float w2 = Wnd1[u*128 + v2];
            fma8(acc1, &xl[u][0], w1);
            fma8(acc2, &xl[128 + u*3 + m2][0], w2);
        }
        float b = bnd0[j];
        #pragma unroll
        for (int n = 0; n < 8; ++n) self_x[(size_t)(n0+n)*512 + j] = acc1[n] + b;
    } else {
        const int o1 = j - 128, v1 = o1/3, m1 = o1%3;
        for (int u = 0; u < 128; ++u){
            float w1 = Wnd1[u*128 + v1];
            float w2 = Wnd1[u*128 + v2];
            fma8(acc1, &xl[128 + u*3 + m1][0], w1);
            fma8(acc2, &xl[128 + u*3 + m2][0], w2);
        }
        #pragma unroll
        for (int n = 0; n < 8; ++n) self_x[(size_t)(n0+n)*512 + j] = acc1[n];
    }
    #pragma unroll
    for (int n = 0; n < 8; ++n) self_x[(size_t)(n0+n)*512 + j + 256] = acc2[n];
}

// ---------------- K3: edge features -> fbuf, sbuf (E x 32 each) ------------
__global__ __launch_bounds__(256) void k_edge_pre(
    const float* __restrict__ p1g, const float* __restrict__ sdst,
    const float* __restrict__ ea, const int* __restrict__ eidx,
    const float* __restrict__ Wf1, const float* __restrict__ Ws1,
    float* __restrict__ fbuf, float* __restrict__ sbuf)
{
    __shared__ float p1d[8][384], p1s[8][384];
    __shared__ float eal[8][32], sdl[8][32];
    __shared__ float ip1l[8][128];
    __shared__ int il[8][2];
    const int tid = threadIdx.x;
    const long e0 = (long)blockIdx.x * 8;

    if (tid < 16){
        int e = tid & 7;
        il[e][tid>>3] = eidx[(size_t)(tid>>3)*EE + e0 + e];
    }
    __syncthreads();

    for (int e = 0; e < 8; ++e){
        int dst = il[e][0], src = il[e][1];
        if (tid < 96)
            ((float4*)p1d[e])[tid] = ((const float4*)(p1g + (size_t)dst*384))[tid];
        else if (tid < 192)
            ((float4*)p1s[e])[tid-96] = ((const float4*)(p1g + (size_t)src*384))[tid-96];
        else if (tid < 200)
            ((float4*)eal[e])[tid-192] = ((const float4*)(ea + (e0+e)*32))[tid-192];
        else if (tid < 208)
            ((float4*)sdl[e])[tid-200] = ((const float4*)(sdst + (size_t)dst*32))[tid-200];
    }
    __syncthreads();

    for (int it = 0; it < 4; ++it){
        int idx = tid + 256*it;
        int e = idx >> 7, u = idx & 127;
        ip1l[e][u] = (p1d[e][u*3]*p1s[e][u*3] + p1d[e][u*3+1]*p1s[e][u*3+1]
                    + p1d[e][u*3+2]*p1s[e][u*3+2]) * (1.f/3.f);
    }
    __syncthreads();

    {
        int e = tid >> 5, h = tid & 31;
        float f = 0.f;
        for (int k = 0; k < 32; ++k) f += eal[e][k] * Wf1[k*32 + h];
        float s = sdl[e][h];
        for (int u = 0; u < 128; ++u) s += ip1l[e][u] * Ws1[(256+u)*32 + h];
        fbuf[(e0+e)*32 + h] = sspf(f);
        sbuf[(e0+e)*32 + h] = sspf(s);
    }
}

// ---------------- K4: fused dual GEMV + combine + atomic scatter -----------
__global__ __launch_bounds__(256) void k_edge_out(
    const float* __restrict__ fbuf, const float* __restrict__ sbuf,
    const float* __restrict__ self_x, const float* __restrict__ esh,
    const int* __restrict__ eidx,
    const float* __restrict__ Wf2, const float* __restrict__ Ws2,
    float* __restrict__ out)
{
    __shared__ float fbl[8][32], sbl[8][32];
    __shared__ float shl[8][4];
    __shared__ int il[8][2];
    const int tid = threadIdx.x;
    const long e0 = (long)blockIdx.x * 8;

    if (tid < 64)        ((float4*)&fbl[0][0])[tid]     = ((const float4*)(fbuf + e0*32))[tid];
    else if (tid < 128)  ((float4*)&sbl[0][0])[tid-64]  = ((const float4*)(sbuf + e0*32))[tid-64];
    else if (tid < 160)  (&shl[0][0])[tid-128]          = esh[e0*4 + (tid-128)];
    else if (tid < 176){ int t = tid-160; int e = t & 7;
                         il[e][t>>3] = eidx[(size_t)(t>>3)*EE + e0 + e]; }
    __syncthreads();

    const int g = tid >> 7;       // 0..1: which 4 edges
    const int u = tid & 127;      // output channel within each quarter
    float af0[4]={0,0,0,0}, af1[4]={0,0,0,0}, af2[4]={0,0,0,0}, af3[4]={0,0,0,0};
    float as0[4]={0,0,0,0}, as1[4]={0,0,0,0}, as2[4]={0,0,0,0}, as3[4]={0,0,0,0};

    for (int k = 0; k < 32; ++k){
        float wfa = Wf2[k*512 + u],       wfb = Wf2[k*512 + 128 + u];
        float wfc = Wf2[k*512 + 256 + u], wfd = Wf2[k*512 + 384 + u];
        float wsa = Ws2[k*512 + u],       wsb = Ws2[k*512 + 128 + u];
        float wsc = Ws2[k*512 + 256 + u], wsd = Ws2[k*512 + 384 + u];
        #pragma unroll
        for (int i = 0; i < 4; ++i){
            int e = g*4 + i;
            float fb = fbl[e][k], sb = sbl[e][k];
            af0[i] += fb*wfa; af1[i] += fb*wfb; af2[i] += fb*wfc; af3[i] += fb*wfd;
            as0[i] += sb*wsa; as1[i] += sb*wsb; as2[i] += sb*wsc; as3[i] += sb*wsd;
        }
    }

    #pragma unroll
    for (int i = 0; i < 4; ++i){
        int e = g*4 + i;
        int dst = il[e][0], src = il[e][1];
        float w1 = af0[i]*as0[i], w2 = af1[i]*as1[i];
        float w3 = af2[i]*as2[i], w4 = af3[i]*as3[i];
        const float* sx = self_x + (size_t)src*512;
        float x0e = sx[u];
        float x10 = sx[128+u*3], x11 = sx[128+u*3+1], x12 = sx[128+u*3+2];
        float sh0 = shl[e][0], s1 = shl[e][1], s2 = shl[e][2], s3 = shl[e][3];
        float dot = x10*s1 + x11*s2 + x12*s3;
        float* op = out + (size_t)dst*512;
        atomicAdd(op + u,           w1*x0e*sh0 + w4*dot*0.57735026919f);
        atomicAdd(op + 128+u*3,     w2*x0e*s1 + w3*x10*sh0);
        atomicAdd(op + 128+u*3+1,   w2*x0e*s2 + w3*x11*sh0);
        atomicAdd(op + 128+u*3+2,   w2*x0e*s3 + w3*x12*sh0);
    }
}

// ---------------- K5: out linear + residual (in-place over d_out) ----------
__global__ __launch_bounds__(256) void k_post(
    const float* __restrict__ self_x, const float* __restrict__ x,
    const float* __restrict__ Wo0, const float* __restrict__ bo0,
    const float* __restrict__ Wo1,
    float* __restrict__ out)
{
    __shared__ float tl[512][8];
    const int tid = threadIdx.x;
    const int n0 = blockIdx.x * 8;

    for (int it = 0; it < 4; ++it){
        int idx = tid + 256*it;
        int node = idx >> 7, o4 = idx & 127;
        float4 a = ((const float4*)(out    + (size_t)(n0+node)*512))[o4];
        float4 b = ((const float4*)(self_x + (size_t)(n0+node)*512))[o4];
        tl[o4*4+0][node]=a.x+b.x; tl[o4*4+1][node]=a.y+b.y;
        tl[o4*4+2][node]=a.z+b.z; tl[o4*4+3][node]=a.w+b.w;
    }
    __syncthreads();

    const int j = tid;
    float acc1[8] = {0,0,0,0,0,0,0,0};
    float acc2[8] = {0,0,0,0,0,0,0,0};
    const int o2 = j + 128;
    const int v2 = o2/3, m2 = o2%3;
    if (j < 128){
        for (int u = 0; u < 128; ++u){
            float w1 = Wo0[u*128 + j];
            float w2 = Wo1[u*128 + v2];
            fma8(acc1, &tl[u][0], w1);
            fma8(acc2, &tl[128 + u*3 + m2][0], w2);
        }
        float b = bo0[j];
        #pragma unroll
        for (int n = 0; n < 8; ++n)
            out[(size_t)(n0+n)*512 + j] = acc1[n] + b + x[(size_t)(n0+n)*512 + j];
    } else {
        const int o1 = j - 128, v1 = o1/3, m1 = o1%3;
        for (int u = 0; u < 128; ++u){
            float w1 = Wo1[u*128 + v1];
            float w2 = Wo1[u*128 + v2];
            fma8(acc1, &tl[128 + u*3 + m1][0], w1);
            fma8(acc2, &tl[128 + u*3 + m2][0], w2);
        }
        #pragma unroll
        for (int n = 0; n < 8; ++n)
            out[(size_t)(n0+n)*512 + j] = acc1[n] + x[(size_t)(n0+n)*512 + j];
    }
    #pragma unroll
    for (int n = 0; n < 8; ++n)
        out[(size_t)(n0+n)*512 + j + 256] = acc2[n] + x[(size_t)(n0+n)*512 + j + 256];
}

// ---------------------------------------------------------------------------
extern "C" void kernel_launch(void* const* d_in, const int* in_sizes, int n_in,
                              void* d_out, int out_size, void* d_ws, size_t ws_size,
                              hipStream_t stream)
{
    const float* x    = (const float*)d_in[0];
    const float* esh  = (const float*)d_in[1];
    const float* ea   = (const float*)d_in[2];
    const int*   eidx = (const int*)  d_in[3];
    const float* Wp0  = (const float*)d_in[4];
    const float* bp0  = (const float*)d_in[5];
    const float* Wp1  = (const float*)d_in[6];
    const float* Wnd0 = (const float*)d_in[7];
    const float* bnd0 = (const float*)d_in[8];
    const float* Wnd1 = (const float*)d_in[9];
    const float* Wg1  = (const float*)d_in[10];
    const float* bg1  = (const float*)d_in[11];
    const float* Wg2  = (const float*)d_in[12];
    const float* bg2  = (const float*)d_in[13];
    const float* Wf1  = (const float*)d_in[14];
    const float* Wf2  = (const float*)d_in[15];
    const float* Ws1  = (const float*)d_in[16];
    const float* Ws2  = (const float*)d_in[17];
    const float* Wo0  = (const float*)d_in[18];
    const float* bo0  = (const float*)d_in[19];
    const float* Wo1  = (const float*)d_in[20];

    float* out  = (float*)d_out;
    float* ws   = (float*)d_ws;
    float* p1   = ws;                              // N*384
    float* sdst = p1   + (size_t)NN*384;           // N*32
    float* sfx  = sdst + (size_t)NN*32;            // N*512
    float* fbuf = sfx  + (size_t)NN*512;           // E*32
    float* sbuf = fbuf + (size_t)EE*32;            // E*32

    hipMemsetAsync(d_out, 0, (size_t)NN*512*sizeof(float), stream);

    k_pre     <<<NN/8, 256, 0, stream>>>(x, Wp0, bp0, Wp1, Ws1, p1, sdst);
    k_gate_nd <<<NN/8, 256, 0, stream>>>(x, Wg1, bg1, Wg2, bg2, Wnd0, bnd0, Wnd1, sfx);
    k_edge_pre<<<EE/8, 256, 0, stream>>>(p1, sdst, ea, eidx, Wf1, Ws1, fbuf, sbuf);
    k_edge_out<<<EE/8, 256, 0, stream>>>(fbuf, sbuf, sfx, esh, eidx, Wf2, Ws2, out);
    k_post    <<<NN/8, 256, 0, stream>>>(sfx, x, Wo0, bo0, Wo1, out);
}